// Round 7
// baseline (283.978 us; speedup 1.0000x reference)
//
#include <hip/hip_runtime.h>

// Problem constants
#define MROWS 512            // B*S
#define VDIM  50257          // vocab
#define KP    50304          // VDIM padded to multiple of 64 (= 64*786)
#define NDIM  1024           // D
#define NST32 1572           // KP/32 K-steps of 32
#define KSPLIT 64
#define PRED_OFF 524288      // 512*1024
#define PP_OFF   524800      // + 512
#define NPREP  4096          // 512 rows x 8 chunks
#define CHUNK  6288          // multiple of 8; 8*6288 >= VDIM
#define NCONVW 12576         // 786*16 transpose tiles

typedef unsigned short u16;
typedef unsigned int   u32;
typedef unsigned long long u64;
typedef __bf16 bf16x8 __attribute__((ext_vector_type(8)));
typedef u16    u16x8  __attribute__((ext_vector_type(8)));
typedef float  f32x4  __attribute__((ext_vector_type(4)));
typedef float  f32x4u __attribute__((ext_vector_type(4), aligned(4)));

__device__ __forceinline__ u16 f2bf(float f) {
  u32 u = __float_as_uint(f);
  u32 r = (u + 0x7fffu + ((u >> 16) & 1u)) >> 16;  // RNE
  return (u16)r;
}

__device__ __forceinline__ void gl_lds16(const u16* g, u16* l) {
  __builtin_amdgcn_global_load_lds(
      (const __attribute__((address_space(1))) u32*)(g),
      (__attribute__((address_space(3))) u32*)(l), 16, 0, 0);
}

// ---------------------------------------------------------------------------
// prep: P row-chunks (copy + argmax + bf16, single pass, 8-elem groups ->
// 16B A-stores, 4 loads in flight). UNFUSED from convw (R1 evidence: fusing
// the two stream types cost ~30 µs of effective BW).
// ---------------------------------------------------------------------------
__global__ __launch_bounds__(256) void prep_kernel(const float* __restrict__ P,
                                                   float* __restrict__ out,
                                                   u16* __restrict__ A,
                                                   u64* __restrict__ amax)
{
  const int tid = threadIdx.x;
  const int bx  = blockIdx.x;
  const int m  = bx >> 3;
  const int c  = bx & 7;
  const int s0 = c * CHUNK;
  const int len = min(VDIM - s0, CHUNK);       // 6288, last chunk 6241
  const float* row = P + (size_t)m * VDIM;
  float*       crw = out + PP_OFF + (size_t)m * VDIM;
  u16*        arow = A + (size_t)m * KP;

  if (tid < 32) { f32x4 z = {}; *(f32x4*)(out + (size_t)m * NDIM + c * 128 + tid * 4) = z; }

  u64 best = 0;  // packed (f32 bits << 32) | (0xFFFF - idx); p>0 so bits>0
#define TRK(val, idx) do { \
    u64 pk = ((u64)__float_as_uint(val) << 32) | (u64)(0xFFFFu - (u32)(idx)); \
    best = best > pk ? best : pk; } while (0)
#define GRP(cc) do {                                                     \
    f32x4u va = *(const f32x4u*)(row + (cc));                            \
    f32x4u vb = *(const f32x4u*)(row + (cc) + 4);                        \
    *(f32x4u*)(crw + (cc))     = va;                                     \
    *(f32x4u*)(crw + (cc) + 4) = vb;                                     \
    u16x8 o;                                                             \
    o[0]=f2bf(va[0]); o[1]=f2bf(va[1]); o[2]=f2bf(va[2]); o[3]=f2bf(va[3]); \
    o[4]=f2bf(vb[0]); o[5]=f2bf(vb[1]); o[6]=f2bf(vb[2]); o[7]=f2bf(vb[3]); \
    *(u16x8*)(arow + (cc)) = o;                                          \
    TRK(va[0],(cc)); TRK(va[1],(cc)+1); TRK(va[2],(cc)+2); TRK(va[3],(cc)+3); \
    TRK(vb[0],(cc)+4); TRK(vb[1],(cc)+5); TRK(vb[2],(cc)+6); TRK(vb[3],(cc)+7); \
  } while (0)

  const int ng = len >> 3;                     // 8-elem groups
  int i = tid;
  for (; i + 256 < ng; i += 512) {             // 4 loads in flight
    const int c0 = s0 + (i << 3);
    const int c1 = c0 + 2048;
    GRP(c0);
    GRP(c1);
  }
  if (i < ng) GRP(s0 + (i << 3));
  if (tid < (len & 7)) {                       // straggler elems (last chunk)
    const int col = s0 + (ng << 3) + tid;
    float v = row[col];
    crw[col] = v;
    arow[col] = f2bf(v);
    TRK(v, col);
  }
#undef GRP
#undef TRK
  if (c == 7 && tid < KP - VDIM) arow[VDIM + tid] = 0;  // K-pad (47 elems)

  __shared__ u64 sb[256];
  sb[tid] = best;
  __syncthreads();
  for (int s = 128; s > 0; s >>= 1) {
    if (tid < s) { u64 o = sb[tid + s]; if (o > sb[tid]) sb[tid] = o; }
    __syncthreads();
  }
  if (tid == 0) atomicMax(&amax[m], sb[0]);
}

// ---------------------------------------------------------------------------
// convw: 64x64 tile transpose+convert W [V][D] f32 -> BT [D][KP] bf16.
// ---------------------------------------------------------------------------
__global__ __launch_bounds__(256) void convw_kernel(const float* __restrict__ W,
                                                    u16* __restrict__ BT)
{
  const int cidx = blockIdx.x;
  __shared__ u16 t[64][65];
  const int tid = threadIdx.x;
  const int dt  = cidx & 15;
  const int vt  = cidx >> 4;          // 0..785; 786*64 == KP exactly
  const int v0  = vt << 6;
  const int d0  = dt << 6;
  const int c16 = tid & 15;
  const int r16 = tid >> 4;
#pragma unroll
  for (int p = 0; p < 4; ++p) {
    const int v  = v0 + p * 16 + r16;
    const int vl = p * 16 + r16;
    float4 w = make_float4(0.f, 0.f, 0.f, 0.f);
    if (v < VDIM) w = *(const float4*)(W + (size_t)v * NDIM + d0 + c16 * 4);
    t[c16 * 4 + 0][vl] = f2bf(w.x);
    t[c16 * 4 + 1][vl] = f2bf(w.y);
    t[c16 * 4 + 2][vl] = f2bf(w.z);
    t[c16 * 4 + 3][vl] = f2bf(w.w);
  }
  __syncthreads();
#pragma unroll
  for (int p = 0; p < 4; ++p) {
    const int dl = p * 16 + r16;
    const int vl = c16 * 4;
    ushort4 o;
    o.x = t[dl][vl]; o.y = t[dl][vl + 1]; o.z = t[dl][vl + 2]; o.w = t[dl][vl + 3];
    *(ushort4*)(BT + (size_t)(d0 + dl) * KP + v0 + vl) = o;
  }
}

// ---------------------------------------------------------------------------
// GEMM: 256x256 tile, BK=32, 8 waves (2m x 4n), RING-2 dbuf (64KB LDS ->
// 2 blocks/CU, 4 waves/SIMD: aggregate staging BW scales with residency),
// counted vmcnt(4) (stage t+2 after read-release barrier, never drains
// mid-loop), paired-row 8-slot XOR swizzle, split-K=64 (512 blocks, balanced
// partition), XCD-grouped decode, atomicAdd f32 epilogue.
// ---------------------------------------------------------------------------
__global__ __launch_bounds__(512, 2) void gemm_kernel(const u16* __restrict__ A,
                                                      const u16* __restrict__ BT,
                                                      const u64* __restrict__ amax,
                                                      float* __restrict__ out)
{
  __shared__ u16 ldsA[2][256 * 32];   // 16KB per buf
  __shared__ u16 ldsB[2][256 * 32];

  const int bx  = blockIdx.x;
  // bits[2:0]=x, [5:3]=mn, [8:6]=z; kc = x | z<<3 -> the 8 mn-blocks of one
  // kc share bx%8 -> same XCD (shared A/B k-panels stay in one L2)
  const int kc  = (bx & 7) | ((bx >> 6) << 3);     // 0..63
  const int mn  = (bx >> 3) & 7;
  const int m0  = (mn & 1) << 8;
  const int n0  = (mn >> 1) << 8;
  const int ks0 = (kc * NST32) >> 6;               // balanced, never empty
  const int ks1 = ((kc + 1) * NST32) >> 6;
  const int tid  = threadIdx.x;
  const int wid  = tid >> 6;
  const int lane = tid & 63;
  const int wr   = wid >> 2;   // 0..1
  const int wc   = wid & 3;    // 0..3

  if (bx == 0) {  // finalize predictions (512 threads, one per row)
    u64 p = amax[tid];
    out[PRED_OFF + tid] = (float)(0xFFFF - (int)(p & 0xFFFFu));
  }

  // --- staging (pre-swizzled source): lane l = p*8+s covers 16B slot s of
  // 128B row-pair p; LDS written linearly; slot s of pair p holds global
  // (row 2p+((s^p)>>2), kslot (s^p)&3)  [both-sides swizzle, rule 21]
  const int sp  = lane >> 3;                  // pair in 16-row band
  const int sx  = (lane & 7) ^ sp;            // swizzled (rowbit,kslot)
  const int srow = 2 * sp + (sx >> 2);        // row in band (0..15)
  const int skel = (sx & 3) << 3;             // k elem offset
  const u16* gA = A  + (size_t)(m0 + wid * 32 + srow) * KP + skel;
  const u16* gB = BT + (size_t)(n0 + wid * 32 + srow) * KP + skel;

  f32x4 acc[8][4] = {};

  // --- fragment read: row r=lane&15, kslot q4=lane>>4; slot within pair:
  const int r   = lane & 15;
  const int q4  = lane >> 4;                  // 0..3
  const int sl  = (((r & 1) << 2) | q4) ^ ((r >> 1) & 7);   // per-lane const
  const int rb2A = (wr * 128 + (r & ~1)) * 32 + sl * 8;
  const int rb2B = (wc * 64  + (r & ~1)) * 32 + sl * 8;

#define STAGE(buf, ks) do {                                              \
    const size_t k_ = (size_t)(ks) << 5;                                 \
    gl_lds16(gA + k_,                 &ldsA[buf][(wid * 32) * 32]);      \
    gl_lds16(gA + k_ + (size_t)16*KP, &ldsA[buf][(wid * 32 + 16) * 32]); \
    gl_lds16(gB + k_,                 &ldsB[buf][(wid * 32) * 32]);      \
    gl_lds16(gB + k_ + (size_t)16*KP, &ldsB[buf][(wid * 32 + 16) * 32]); \
  } while (0)

  STAGE(0, ks0);
  if (ks0 + 1 < ks1) STAGE(1, ks0 + 1);

  int b = 0;
  for (int ks = ks0; ks < ks1; ++ks) {
    // wait for step ks's 4 loads (step ks+1's may stay in flight)
    if (ks + 1 < ks1) asm volatile("s_waitcnt vmcnt(4)" ::: "memory");
    else              asm volatile("s_waitcnt vmcnt(0)" ::: "memory");
    __builtin_amdgcn_s_barrier();

    const u16* lA = ldsA[b];
    const u16* lB = ldsB[b];
    bf16x8 av[8], bv[4];
#pragma unroll
    for (int i = 0; i < 8; ++i) av[i] = *(const bf16x8*)(lA + rb2A + i * 512);
#pragma unroll
    for (int j = 0; j < 4; ++j) bv[j] = *(const bf16x8*)(lB + rb2B + j * 512);

    __builtin_amdgcn_s_setprio(1);
#pragma unroll
    for (int i = 0; i < 8; ++i)
#pragma unroll
      for (int j = 0; j < 4; ++j)
        acc[i][j] = __builtin_amdgcn_mfma_f32_16x16x32_bf16(av[i], bv[j], acc[i][j], 0, 0, 0);
    __builtin_amdgcn_s_setprio(0);

    __builtin_amdgcn_s_barrier();       // all waves done reading buf b
    if (ks + 2 < ks1) STAGE(b, ks + 2); // overwrite just-freed buffer
    b ^= 1;
  }
#undef STAGE

  // epilogue: split-K accumulate (pred_emb zeroed by prep)
  const int col = lane & 15;
  const int r4  = q4 << 2;
#pragma unroll
  for (int i = 0; i < 8; ++i)
#pragma unroll
    for (int j = 0; j < 4; ++j)
#pragma unroll
      for (int rr = 0; rr < 4; ++rr) {
        const int mm = m0 + wr * 128 + i * 16 + r4 + rr;
        const int nn = n0 + wc * 64 + j * 16 + col;
        atomicAdd(out + (size_t)mm * NDIM + nn, acc[i][j][rr]);
      }
}

// ---------------------------------------------------------------------------
extern "C" void kernel_launch(void* const* d_in, const int* in_sizes, int n_in,
                              void* d_out, int out_size, void* d_ws, size_t ws_size,
                              hipStream_t stream) {
  const float* P = (const float*)d_in[0];   // [512][50257]
  const float* W = (const float*)d_in[1];   // [50257][1024]
  float* out = (float*)d_out;
  u64* amax = (u64*)d_ws;                               // 512 x u64
  u16* A  = (u16*)((char*)d_ws + 4096);                 // [512][KP] bf16
  u16* BT = A + (size_t)MROWS * KP;                     // [1024][KP] bf16

  hipMemsetAsync(amax, 0, MROWS * sizeof(u64), stream);
  prep_kernel<<<NPREP, 256, 0, stream>>>(P, out, A, amax);
  convw_kernel<<<NCONVW, 256, 0, stream>>>(W, BT);
  gemm_kernel<<<512, 512, 0, stream>>>(A, BT, amax, out);
}

// Round 8
// 239.035 us; speedup vs baseline: 1.1880x; 1.1880x over previous
//
#include <hip/hip_runtime.h>

// Problem constants
#define MROWS 512            // B*S
#define VDIM  50257          // vocab
#define KP    50304          // VDIM padded to multiple of 64 (= 64*786)
#define NDIM  1024           // D
#define NST32 1572           // KP/32 K-steps of 32
#define KSPLIT 32
#define SC     50            // 32*50 = 1600 >= 1572 (last chunk 22 steps)
#define PRED_OFF 524288      // 512*1024
#define PP_OFF   524800      // + 512
#define NPREP  4096          // 512 rows x 8 chunks
#define CHUNK  6288          // multiple of 8; 8*6288 >= VDIM
#define NCONVW 12576         // 786*16 transpose tiles

typedef unsigned short u16;
typedef unsigned int   u32;
typedef unsigned long long u64;
typedef __bf16 bf16x8 __attribute__((ext_vector_type(8)));
typedef u16    u16x8  __attribute__((ext_vector_type(8)));
typedef float  f32x4  __attribute__((ext_vector_type(4)));
typedef float  f32x4u __attribute__((ext_vector_type(4), aligned(4)));

__device__ __forceinline__ u16 f2bf(float f) {
  u32 u = __float_as_uint(f);
  u32 r = (u + 0x7fffu + ((u >> 16) & 1u)) >> 16;  // RNE
  return (u16)r;
}

__device__ __forceinline__ void gl_lds16(const u16* g, u16* l) {
  __builtin_amdgcn_global_load_lds(
      (const __attribute__((address_space(1))) u32*)(g),
      (__attribute__((address_space(3))) u32*)(l), 16, 0, 0);
}

// ---------------------------------------------------------------------------
// prep: P row-chunks (copy + argmax + bf16, single pass, 8-elem groups ->
// 16B A-stores, 4 loads in flight). Unfused from convw (R7: fusing cost ~30us).
// ---------------------------------------------------------------------------
__global__ __launch_bounds__(256) void prep_kernel(const float* __restrict__ P,
                                                   float* __restrict__ out,
                                                   u16* __restrict__ A,
                                                   u64* __restrict__ amax)
{
  const int tid = threadIdx.x;
  const int bx  = blockIdx.x;
  const int m  = bx >> 3;
  const int c  = bx & 7;
  const int s0 = c * CHUNK;
  const int len = min(VDIM - s0, CHUNK);       // 6288, last chunk 6241
  const float* row = P + (size_t)m * VDIM;
  float*       crw = out + PP_OFF + (size_t)m * VDIM;
  u16*        arow = A + (size_t)m * KP;

  if (tid < 32) { f32x4 z = {}; *(f32x4*)(out + (size_t)m * NDIM + c * 128 + tid * 4) = z; }

  u64 best = 0;  // packed (f32 bits << 32) | (0xFFFF - idx); p>0 so bits>0
#define TRK(val, idx) do { \
    u64 pk = ((u64)__float_as_uint(val) << 32) | (u64)(0xFFFFu - (u32)(idx)); \
    best = best > pk ? best : pk; } while (0)
#define GRP(cc) do {                                                     \
    f32x4u va = *(const f32x4u*)(row + (cc));                            \
    f32x4u vb = *(const f32x4u*)(row + (cc) + 4);                        \
    *(f32x4u*)(crw + (cc))     = va;                                     \
    *(f32x4u*)(crw + (cc) + 4) = vb;                                     \
    u16x8 o;                                                             \
    o[0]=f2bf(va[0]); o[1]=f2bf(va[1]); o[2]=f2bf(va[2]); o[3]=f2bf(va[3]); \
    o[4]=f2bf(vb[0]); o[5]=f2bf(vb[1]); o[6]=f2bf(vb[2]); o[7]=f2bf(vb[3]); \
    *(u16x8*)(arow + (cc)) = o;                                          \
    TRK(va[0],(cc)); TRK(va[1],(cc)+1); TRK(va[2],(cc)+2); TRK(va[3],(cc)+3); \
    TRK(vb[0],(cc)+4); TRK(vb[1],(cc)+5); TRK(vb[2],(cc)+6); TRK(vb[3],(cc)+7); \
  } while (0)

  const int ng = len >> 3;                     // 8-elem groups
  int i = tid;
  for (; i + 256 < ng; i += 512) {             // 4 loads in flight
    const int c0 = s0 + (i << 3);
    const int c1 = c0 + 2048;
    GRP(c0);
    GRP(c1);
  }
  if (i < ng) GRP(s0 + (i << 3));
  if (tid < (len & 7)) {                       // straggler elems (last chunk)
    const int col = s0 + (ng << 3) + tid;
    float v = row[col];
    crw[col] = v;
    arow[col] = f2bf(v);
    TRK(v, col);
  }
#undef GRP
#undef TRK
  if (c == 7 && tid < KP - VDIM) arow[VDIM + tid] = 0;  // K-pad (47 elems)

  __shared__ u64 sb[256];
  sb[tid] = best;
  __syncthreads();
  for (int s = 128; s > 0; s >>= 1) {
    if (tid < s) { u64 o = sb[tid + s]; if (o > sb[tid]) sb[tid] = o; }
    __syncthreads();
  }
  if (tid == 0) atomicMax(&amax[m], sb[0]);
}

// ---------------------------------------------------------------------------
// convw: 64x64 tile transpose+convert W [V][D] f32 -> BT [D][KP] bf16.
// 16B (u16x8) BT stores: 8 lanes cover one 64-col row = 128B segment.
// LDS pad 72 (144B rows, 16B-aligned; read banks 2-way = free).
// ---------------------------------------------------------------------------
__global__ __launch_bounds__(256) void convw_kernel(const float* __restrict__ W,
                                                    u16* __restrict__ BT)
{
  const int cidx = blockIdx.x;
  __shared__ u16 t[64][72];
  const int tid = threadIdx.x;
  const int dt  = cidx & 15;
  const int vt  = cidx >> 4;          // 0..785; 786*64 == KP exactly
  const int v0  = vt << 6;
  const int d0  = dt << 6;
  const int c16 = tid & 15;
  const int r16 = tid >> 4;
#pragma unroll
  for (int p = 0; p < 4; ++p) {
    const int v  = v0 + p * 16 + r16;
    const int vl = p * 16 + r16;
    float4 w = make_float4(0.f, 0.f, 0.f, 0.f);
    if (v < VDIM) w = *(const float4*)(W + (size_t)v * NDIM + d0 + c16 * 4);
    t[c16 * 4 + 0][vl] = f2bf(w.x);
    t[c16 * 4 + 1][vl] = f2bf(w.y);
    t[c16 * 4 + 2][vl] = f2bf(w.z);
    t[c16 * 4 + 3][vl] = f2bf(w.w);
  }
  __syncthreads();
  // write: 8 passes; lane -> (row = p*8 + tid>>5, col8 = (tid&31)... 256 thr:
  // per pass 256 lanes cover 32 rows? Use: row = p*32 + (tid>>3), col8=(tid&7)*8
#pragma unroll
  for (int p = 0; p < 2; ++p) {
    const int dl = p * 32 + (tid >> 3);        // 0..63
    const int vl = (tid & 7) * 8;              // 0..56
    u16x8 o = *(const u16x8*)(&t[dl][vl]);     // 16B-aligned (144B rows)
    *(u16x8*)(BT + (size_t)(d0 + dl) * KP + v0 + vl) = o;
  }
}

// ---------------------------------------------------------------------------
// GEMM (R4-proven schedule + R6 conflict-free swizzle):
// 256x256 tile, BK=32, 8 waves (2m x 4n), 4-buffer LDS ring (128KB),
// depth-3 prefetch, counted vmcnt (8/4/0 — never drains mid-loop),
// ONE barrier per K-step (stage ks+3 right after barrier: that buffer was
// last read in step ks-1, proven finished by this barrier), paired-row
// 8-slot XOR swizzle (pre-swizzled global source + swizzled ds_read = exactly
// 2-way banks = free), split-K=32 (256 blocks = 1/CU), XCD-grouped decode,
// atomicAdd f32 epilogue.
// ---------------------------------------------------------------------------
__global__ __launch_bounds__(512, 1) void gemm_kernel(const u16* __restrict__ A,
                                                      const u16* __restrict__ BT,
                                                      const u64* __restrict__ amax,
                                                      float* __restrict__ out)
{
  __shared__ u16 ldsA[4][256 * 32];   // 16KB per buf
  __shared__ u16 ldsB[4][256 * 32];

  const int bx  = blockIdx.x;
  // bits[2:0]=x, [5:3]=mn, [7:6]=z; kc = x | z<<3 -> the 8 mn-blocks of one
  // kc share bx%8 -> same XCD (shared A/B k-panels stay in one L2)
  const int kc  = (bx & 7) | ((bx >> 6) << 3);     // 0..31
  const int mn  = (bx >> 3) & 7;
  const int m0  = (mn & 1) << 8;
  const int n0  = (mn >> 1) << 8;
  const int ks0 = kc * SC;
  const int ks1 = min(NST32, ks0 + SC);
  const int tid  = threadIdx.x;
  const int wid  = tid >> 6;
  const int lane = tid & 63;
  const int wr   = wid >> 2;   // 0..1
  const int wc   = wid & 3;    // 0..3

  if (bx == 0) {  // finalize predictions (512 threads, one per row)
    u64 p = amax[tid];
    out[PRED_OFF + tid] = (float)(0xFFFF - (int)(p & 0xFFFFu));
  }

  // --- staging (pre-swizzled source): lane l = p*8+s covers 16B slot s of
  // 128B row-pair p; LDS written linearly; slot s of pair p holds global
  // (row 2p+((s^p)>>2), kslot (s^p)&3)  [both-sides swizzle, rule 21]
  const int sp  = lane >> 3;                  // pair in 16-row band
  const int sx  = (lane & 7) ^ sp;            // swizzled (rowbit,kslot)
  const int srow = 2 * sp + (sx >> 2);        // row in band (0..15)
  const int skel = (sx & 3) << 3;             // k elem offset
  const u16* gA = A  + (size_t)(m0 + wid * 32 + srow) * KP + skel;
  const u16* gB = BT + (size_t)(n0 + wid * 32 + srow) * KP + skel;

  f32x4 acc[8][4] = {};

  // --- fragment read: row r=lane&15, kslot q4=lane>>4; slot within pair:
  const int r   = lane & 15;
  const int q4  = lane >> 4;                  // 0..3
  const int sl  = (((r & 1) << 2) | q4) ^ ((r >> 1) & 7);   // per-lane const
  const int rb2A = (wr * 128 + (r & ~1)) * 32 + sl * 8;
  const int rb2B = (wc * 64  + (r & ~1)) * 32 + sl * 8;

#define STAGE(buf, ks) do {                                              \
    const size_t k_ = (size_t)(ks) << 5;                                 \
    gl_lds16(gA + k_,                 &ldsA[buf][(wid * 32) * 32]);      \
    gl_lds16(gA + k_ + (size_t)16*KP, &ldsA[buf][(wid * 32 + 16) * 32]); \
    gl_lds16(gB + k_,                 &ldsB[buf][(wid * 32) * 32]);      \
    gl_lds16(gB + k_ + (size_t)16*KP, &ldsB[buf][(wid * 32 + 16) * 32]); \
  } while (0)

  STAGE(0, ks0);
  if (ks0 + 1 < ks1) STAGE(1, ks0 + 1);
  if (ks0 + 2 < ks1) STAGE(2, ks0 + 2);

  int b = 0;
  for (int ks = ks0; ks < ks1; ++ks) {
    // wait for step ks's 4 loads (ks+1, ks+2's 8 may stay in flight)
    if (ks + 2 < ks1)      asm volatile("s_waitcnt vmcnt(8) lgkmcnt(0)" ::: "memory");
    else if (ks + 1 < ks1) asm volatile("s_waitcnt vmcnt(4) lgkmcnt(0)" ::: "memory");
    else                   asm volatile("s_waitcnt vmcnt(0) lgkmcnt(0)" ::: "memory");
    __builtin_amdgcn_s_barrier();
    // barrier proves step ks-1's reads done -> safe to overwrite buf (b+3)&3
    if (ks + 3 < ks1) STAGE((b + 3) & 3, ks + 3);

    const u16* lA = ldsA[b];
    const u16* lB = ldsB[b];
    bf16x8 av[8], bv[4];
#pragma unroll
    for (int i = 0; i < 8; ++i) av[i] = *(const bf16x8*)(lA + rb2A + i * 512);
#pragma unroll
    for (int j = 0; j < 4; ++j) bv[j] = *(const bf16x8*)(lB + rb2B + j * 512);

    __builtin_amdgcn_s_setprio(1);
#pragma unroll
    for (int i = 0; i < 8; ++i)
#pragma unroll
      for (int j = 0; j < 4; ++j)
        acc[i][j] = __builtin_amdgcn_mfma_f32_16x16x32_bf16(av[i], bv[j], acc[i][j], 0, 0, 0);
    __builtin_amdgcn_s_setprio(0);
    __builtin_amdgcn_sched_barrier(0);  // pin MFMAs here (rule 18)
    b = (b + 1) & 3;
  }
#undef STAGE

  // epilogue: split-K accumulate (pred_emb zeroed by prep)
  const int col = lane & 15;
  const int r4  = q4 << 2;
#pragma unroll
  for (int i = 0; i < 8; ++i)
#pragma unroll
    for (int j = 0; j < 4; ++j)
#pragma unroll
      for (int rr = 0; rr < 4; ++rr) {
        const int mm = m0 + wr * 128 + i * 16 + r4 + rr;
        const int nn = n0 + wc * 64 + j * 16 + col;
        atomicAdd(out + (size_t)mm * NDIM + nn, acc[i][j][rr]);
      }
}

// ---------------------------------------------------------------------------
extern "C" void kernel_launch(void* const* d_in, const int* in_sizes, int n_in,
                              void* d_out, int out_size, void* d_ws, size_t ws_size,
                              hipStream_t stream) {
  const float* P = (const float*)d_in[0];   // [512][50257]
  const float* W = (const float*)d_in[1];   // [50257][1024]
  float* out = (float*)d_out;
  u64* amax = (u64*)d_ws;                               // 512 x u64
  u16* A  = (u16*)((char*)d_ws + 4096);                 // [512][KP] bf16
  u16* BT = A + (size_t)MROWS * KP;                     // [1024][KP] bf16

  hipMemsetAsync(amax, 0, MROWS * sizeof(u64), stream);
  prep_kernel<<<NPREP, 256, 0, stream>>>(P, out, A, amax);
  convw_kernel<<<NCONVW, 256, 0, stream>>>(W, BT);
  gemm_kernel<<<256, 512, 0, stream>>>(A, BT, amax, out);
}

// Round 9
// 217.875 us; speedup vs baseline: 1.3034x; 1.0971x over previous
//
#include <hip/hip_runtime.h>

// Problem constants
#define MROWS 512            // B*S
#define VDIM  50257          // vocab
#define KP    50304          // VDIM padded to multiple of 64 (= 64*786)
#define NDIM  1024           // D
#define NST32 1572           // KP/32 K-steps of 32
#define KSPLIT 32
#define PRED_OFF 524288      // 512*1024
#define PP_OFF   524800      // + 512
#define NPREP  4096          // 512 rows x 8 chunks
#define CHUNK  6288          // multiple of 8; 8*6288 >= VDIM
#define NCONVW 12576         // 786*16 transpose tiles

typedef unsigned short u16;
typedef unsigned int   u32;
typedef unsigned long long u64;
typedef __bf16 bf16x8 __attribute__((ext_vector_type(8)));
typedef u16    u16x8  __attribute__((ext_vector_type(8)));
typedef float  f32x4  __attribute__((ext_vector_type(4)));
typedef float  f32x4u __attribute__((ext_vector_type(4), aligned(4)));

__device__ __forceinline__ u16 f2bf(float f) {
  u32 u = __float_as_uint(f);
  u32 r = (u + 0x7fffu + ((u >> 16) & 1u)) >> 16;  // RNE
  return (u16)r;
}

__device__ __forceinline__ void gl_lds16(const u16* g, u16* l) {
  __builtin_amdgcn_global_load_lds(
      (const __attribute__((address_space(1))) u32*)(g),
      (__attribute__((address_space(3))) u32*)(l), 16, 0, 0);
}

// ---------------------------------------------------------------------------
// prep: P row-chunks (copy + argmax + bf16, single pass, 8-elem groups ->
// 16B A-stores, 4 loads in flight).
// ---------------------------------------------------------------------------
__global__ __launch_bounds__(256) void prep_kernel(const float* __restrict__ P,
                                                   float* __restrict__ out,
                                                   u16* __restrict__ A,
                                                   u64* __restrict__ amax)
{
  const int tid = threadIdx.x;
  const int bx  = blockIdx.x;
  const int m  = bx >> 3;
  const int c  = bx & 7;
  const int s0 = c * CHUNK;
  const int len = min(VDIM - s0, CHUNK);       // 6288, last chunk 6241
  const float* row = P + (size_t)m * VDIM;
  float*       crw = out + PP_OFF + (size_t)m * VDIM;
  u16*        arow = A + (size_t)m * KP;

  if (tid < 32) { f32x4 z = {}; *(f32x4*)(out + (size_t)m * NDIM + c * 128 + tid * 4) = z; }

  u64 best = 0;  // packed (f32 bits << 32) | (0xFFFF - idx); p>0 so bits>0
#define TRK(val, idx) do { \
    u64 pk = ((u64)__float_as_uint(val) << 32) | (u64)(0xFFFFu - (u32)(idx)); \
    best = best > pk ? best : pk; } while (0)
#define GRP(cc) do {                                                     \
    f32x4u va = *(const f32x4u*)(row + (cc));                            \
    f32x4u vb = *(const f32x4u*)(row + (cc) + 4);                        \
    *(f32x4u*)(crw + (cc))     = va;                                     \
    *(f32x4u*)(crw + (cc) + 4) = vb;                                     \
    u16x8 o;                                                             \
    o[0]=f2bf(va[0]); o[1]=f2bf(va[1]); o[2]=f2bf(va[2]); o[3]=f2bf(va[3]); \
    o[4]=f2bf(vb[0]); o[5]=f2bf(vb[1]); o[6]=f2bf(vb[2]); o[7]=f2bf(vb[3]); \
    *(u16x8*)(arow + (cc)) = o;                                          \
    TRK(va[0],(cc)); TRK(va[1],(cc)+1); TRK(va[2],(cc)+2); TRK(va[3],(cc)+3); \
    TRK(vb[0],(cc)+4); TRK(vb[1],(cc)+5); TRK(vb[2],(cc)+6); TRK(vb[3],(cc)+7); \
  } while (0)

  const int ng = len >> 3;                     // 8-elem groups
  int i = tid;
  for (; i + 256 < ng; i += 512) {             // 4 loads in flight
    const int c0 = s0 + (i << 3);
    const int c1 = c0 + 2048;
    GRP(c0);
    GRP(c1);
  }
  if (i < ng) GRP(s0 + (i << 3));
  if (tid < (len & 7)) {                       // straggler elems (last chunk)
    const int col = s0 + (ng << 3) + tid;
    float v = row[col];
    crw[col] = v;
    arow[col] = f2bf(v);
    TRK(v, col);
  }
#undef GRP
#undef TRK
  if (c == 7 && tid < KP - VDIM) arow[VDIM + tid] = 0;  // K-pad (47 elems)

  __shared__ u64 sb[256];
  sb[tid] = best;
  __syncthreads();
  for (int s = 128; s > 0; s >>= 1) {
    if (tid < s) { u64 o = sb[tid + s]; if (o > sb[tid]) sb[tid] = o; }
    __syncthreads();
  }
  if (tid == 0) atomicMax(&amax[m], sb[0]);
}

// ---------------------------------------------------------------------------
// convw: 64x64 tile transpose+convert W [V][D] f32 -> BT [D][KP] bf16.
// ---------------------------------------------------------------------------
__global__ __launch_bounds__(256) void convw_kernel(const float* __restrict__ W,
                                                    u16* __restrict__ BT)
{
  const int cidx = blockIdx.x;
  __shared__ u16 t[64][72];
  const int tid = threadIdx.x;
  const int dt  = cidx & 15;
  const int vt  = cidx >> 4;          // 0..785; 786*64 == KP exactly
  const int v0  = vt << 6;
  const int d0  = dt << 6;
  const int c16 = tid & 15;
  const int r16 = tid >> 4;
#pragma unroll
  for (int p = 0; p < 4; ++p) {
    const int v  = v0 + p * 16 + r16;
    const int vl = p * 16 + r16;
    float4 w = make_float4(0.f, 0.f, 0.f, 0.f);
    if (v < VDIM) w = *(const float4*)(W + (size_t)v * NDIM + d0 + c16 * 4);
    t[c16 * 4 + 0][vl] = f2bf(w.x);
    t[c16 * 4 + 1][vl] = f2bf(w.y);
    t[c16 * 4 + 2][vl] = f2bf(w.z);
    t[c16 * 4 + 3][vl] = f2bf(w.w);
  }
  __syncthreads();
#pragma unroll
  for (int p = 0; p < 2; ++p) {
    const int dl = p * 32 + (tid >> 3);        // 0..63
    const int vl = (tid & 7) * 8;              // 0..56
    u16x8 o = *(const u16x8*)(&t[dl][vl]);     // 16B-aligned (144B rows)
    *(u16x8*)(BT + (size_t)(d0 + dl) * KP + v0 + vl) = o;
  }
}

// ---------------------------------------------------------------------------
// GEMM: 128x128 tile, BK=32, 4 waves (2m x 2n), ring-2 LDS (32KB -> up to
// 5 blocks/CU; grid 1024 = 4 resident blocks/CU for cross-block latency
// hiding, the m97-proven regime), single barrier + vmcnt(0) per K-step,
// paired-row 8-slot XOR swizzle (2-way banks = free), split-K=32,
// XCD decode (the 32 blocks of one kc share one XCD's L2).
// TS=1: plain partial-tile stores to Pp (reduced by reduce_kernel).
// TS=0: atomicAdd fallback (pred_emb zeroed by prep).
// ---------------------------------------------------------------------------
template <int TS>
__global__ __launch_bounds__(256, 4) void gemm_kernel(const u16* __restrict__ A,
                                                      const u16* __restrict__ BT,
                                                      const u64* __restrict__ amax,
                                                      float* __restrict__ out,
                                                      float* __restrict__ Pp)
{
  __shared__ u16 ldsA[2][128 * 32];   // 8KB per buf
  __shared__ u16 ldsB[2][128 * 32];

  const int bx  = blockIdx.x;
  // decode: x = bx&7 (XCD), s = bx>>3; kc = x + 8*(s>>5), mn = s&31.
  // All 32 mn-blocks of a kc land on XCD x -> its A/B k-slabs live in one L2.
  const int x   = bx & 7;
  const int s   = bx >> 3;
  const int kc  = x + ((s >> 5) << 3);   // 0..31
  const int mn  = s & 31;
  const int mt  = mn & 3;                // 4 m-tiles of 128
  const int nt  = mn >> 2;               // 8 n-tiles of 128
  const int m0  = mt << 7;
  const int n0  = nt << 7;
  const int ks0 = (kc * NST32) / KSPLIT;
  const int ks1 = ((kc + 1) * NST32) / KSPLIT;
  const int tid  = threadIdx.x;
  const int wid  = tid >> 6;
  const int lane = tid & 63;
  const int wr   = wid >> 1;   // 0..1
  const int wc   = wid & 1;    // 0..1

  if (bx == 0) {  // finalize predictions (256 threads -> 2 rows each)
    u64 p0 = amax[tid];
    u64 p1 = amax[tid + 256];
    out[PRED_OFF + tid]       = (float)(0xFFFF - (int)(p0 & 0xFFFFu));
    out[PRED_OFF + tid + 256] = (float)(0xFFFF - (int)(p1 & 0xFFFFu));
  }

  // staging (pre-swizzled source): lane l = p*8+s covers 16B slot s of 128B
  // row-pair p within a 16-row band; LDS written linearly; slot s of pair p
  // holds global (row 2p+((s^p)>>2), kslot (s^p)&3)   [validated R6/R8]
  const int sp   = lane >> 3;
  const int sx   = (lane & 7) ^ sp;
  const int srow = 2 * sp + (sx >> 2);
  const int skel = (sx & 3) << 3;
  const u16* gA = A  + (size_t)(m0 + wid * 32 + srow) * KP + skel;
  const u16* gB = BT + (size_t)(n0 + wid * 32 + srow) * KP + skel;

  f32x4 acc[4][4] = {};

  // fragment read: global row r in band, kslot q4 -> swizzled slot sl
  const int r   = lane & 15;
  const int q4  = lane >> 4;
  const int sl  = (((r & 1) << 2) | q4) ^ ((r >> 1) & 7);
  const int rb2A = (wr * 64 + (r & ~1)) * 32 + sl * 8;
  const int rb2B = (wc * 64 + (r & ~1)) * 32 + sl * 8;

#define STAGE(buf, ks) do {                                              \
    const size_t k_ = (size_t)(ks) << 5;                                 \
    gl_lds16(gA + k_,                 &ldsA[buf][(wid * 32) * 32]);      \
    gl_lds16(gA + k_ + (size_t)16*KP, &ldsA[buf][(wid * 32 + 16) * 32]); \
    gl_lds16(gB + k_,                 &ldsB[buf][(wid * 32) * 32]);      \
    gl_lds16(gB + k_ + (size_t)16*KP, &ldsB[buf][(wid * 32 + 16) * 32]); \
  } while (0)

  STAGE(0, ks0);

  int b = 0;
  for (int ks = ks0; ks < ks1; ++ks) {
    asm volatile("s_waitcnt vmcnt(0)" ::: "memory");  // buf b landed (mine)
    __builtin_amdgcn_s_barrier();                     // ..and everyone's;
                                                      // also: all reads of
                                                      // buf b^1 are done
    if (ks + 1 < ks1) STAGE(b ^ 1, ks + 1);           // prefetch next step

    const u16* lA = ldsA[b];
    const u16* lB = ldsB[b];
    bf16x8 av[4], bv[4];
#pragma unroll
    for (int i = 0; i < 4; ++i) av[i] = *(const bf16x8*)(lA + rb2A + i * 512);
#pragma unroll
    for (int j = 0; j < 4; ++j) bv[j] = *(const bf16x8*)(lB + rb2B + j * 512);

    __builtin_amdgcn_s_setprio(1);
#pragma unroll
    for (int i = 0; i < 4; ++i)
#pragma unroll
      for (int j = 0; j < 4; ++j)
        acc[i][j] = __builtin_amdgcn_mfma_f32_16x16x32_bf16(av[i], bv[j], acc[i][j], 0, 0, 0);
    __builtin_amdgcn_s_setprio(0);
    __builtin_amdgcn_sched_barrier(0);
    b ^= 1;
  }
#undef STAGE

  const int col = lane & 15;
  if (TS) {
    // plain partial-tile store: Pp[bx][128][128]
    float* pp = Pp + (size_t)bx * 16384;
#pragma unroll
    for (int i = 0; i < 4; ++i)
#pragma unroll
      for (int j = 0; j < 4; ++j)
#pragma unroll
        for (int rr = 0; rr < 4; ++rr) {
          const int mm = wr * 64 + i * 16 + q4 * 4 + rr;
          const int nn = wc * 64 + j * 16 + col;
          pp[mm * 128 + nn] = acc[i][j][rr];
        }
  } else {
#pragma unroll
    for (int i = 0; i < 4; ++i)
#pragma unroll
      for (int j = 0; j < 4; ++j)
#pragma unroll
        for (int rr = 0; rr < 4; ++rr) {
          const int mm = m0 + wr * 64 + i * 16 + q4 * 4 + rr;
          const int nn = n0 + wc * 64 + j * 16 + col;
          atomicAdd(out + (size_t)mm * NDIM + nn, acc[i][j][rr]);
        }
  }
}

// ---------------------------------------------------------------------------
// reduce: out[m][n] = sum over 32 kc-partials. 512 blocks x 256 thr; each
// thread owns one f32x4 n-quad. 32 independent 16B loads, 4 accumulators.
// ---------------------------------------------------------------------------
__global__ __launch_bounds__(256) void reduce_kernel(const float* __restrict__ Pp,
                                                     float* __restrict__ out)
{
  const int t   = blockIdx.x * 256 + threadIdx.x;  // 0..131071
  const int m   = t >> 8;                          // 0..511
  const int n0q = (t & 255) << 2;                  // 0..1020
  const int mt  = m >> 7;
  const int nt  = n0q >> 7;
  const size_t base = (size_t)(m & 127) * 128 + (n0q & 127);

  f32x4 sacc[4] = {};
#pragma unroll
  for (int kc = 0; kc < 32; ++kc) {
    const int bxp = (((kc >> 3) * 32 + (nt << 2) + mt) << 3) + (kc & 7);
    f32x4 v = *(const f32x4*)(Pp + (size_t)bxp * 16384 + base);
    sacc[kc & 3] += v;
  }
  f32x4 rsum = (sacc[0] + sacc[1]) + (sacc[2] + sacc[3]);
  *(f32x4*)(out + (size_t)m * NDIM + n0q) = rsum;
}

// ---------------------------------------------------------------------------
extern "C" void kernel_launch(void* const* d_in, const int* in_sizes, int n_in,
                              void* d_out, int out_size, void* d_ws, size_t ws_size,
                              hipStream_t stream) {
  const float* P = (const float*)d_in[0];   // [512][50257]
  const float* W = (const float*)d_in[1];   // [50257][1024]
  float* out = (float*)d_out;
  u64* amax = (u64*)d_ws;                               // 512 x u64
  u16* A  = (u16*)((char*)d_ws + 4096);                 // [512][KP] bf16
  u16* BT = A + (size_t)MROWS * KP;                     // [1024][KP] bf16
  const size_t pp_off = 4096 + (size_t)MROWS * KP * 2 + (size_t)NDIM * KP * 2;
  const size_t pp_bytes = (size_t)1024 * 16384 * 4;     // 67.1 MB
  float* Pp = (float*)((char*)d_ws + pp_off);
  const bool two_stage = (ws_size >= pp_off + pp_bytes);

  hipMemsetAsync(amax, 0, MROWS * sizeof(u64), stream);
  prep_kernel<<<NPREP, 256, 0, stream>>>(P, out, A, amax);
  convw_kernel<<<NCONVW, 256, 0, stream>>>(W, BT);
  if (two_stage) {
    gemm_kernel<1><<<1024, 256, 0, stream>>>(A, BT, amax, out, Pp);
    reduce_kernel<<<512, 256, 0, stream>>>(Pp, out);
  } else {
    gemm_kernel<0><<<1024, 256, 0, stream>>>(A, BT, amax, out, Pp);
  }
}

// Round 10
// 209.529 us; speedup vs baseline: 1.3553x; 1.0398x over previous
//
#include <hip/hip_runtime.h>

// Problem constants
#define MROWS 512            // B*S
#define VDIM  50257          // vocab
#define KP    50304          // VDIM padded to multiple of 64 (= 64*786)
#define NDIM  1024           // D
#define NST32 1572           // KP/32 K-steps of 32
#define KSPLIT 32
#define PRED_OFF 524288      // 512*1024
#define PP_OFF   524800      // + 512
#define NPREP  4096          // 512 rows x 8 chunks
#define CHUNK  6288          // multiple of 8; 8*6288 >= VDIM
#define NCONVW 12576         // 786*16 transpose tiles

typedef unsigned short u16;
typedef unsigned int   u32;
typedef unsigned long long u64;
typedef __bf16 bf16x8 __attribute__((ext_vector_type(8)));
typedef u16    u16x8  __attribute__((ext_vector_type(8)));
typedef float  f32x4  __attribute__((ext_vector_type(4)));
typedef float  f32x4u __attribute__((ext_vector_type(4), aligned(4)));

__device__ __forceinline__ u16 f2bf(float f) {
  u32 u = __float_as_uint(f);
  u32 r = (u + 0x7fffu + ((u >> 16) & 1u)) >> 16;  // RNE
  return (u16)r;
}

__device__ __forceinline__ void gl_lds16(const u16* g, u16* l) {
  __builtin_amdgcn_global_load_lds(
      (const __attribute__((address_space(1))) u32*)(g),
      (__attribute__((address_space(3))) u32*)(l), 16, 0, 0);
}

// ---------------------------------------------------------------------------
// prep: P row-chunks (copy + argmax + bf16, single pass, 8-elem groups ->
// 16B A-stores, 4 loads in flight). Argmax partial -> plain store to part[]
// (no init / no atomics needed; gemm block 0 reduces the 8 per row).
// ---------------------------------------------------------------------------
__global__ __launch_bounds__(256) void prep_kernel(const float* __restrict__ P,
                                                   float* __restrict__ out,
                                                   u16* __restrict__ A,
                                                   u64* __restrict__ part)
{
  const int tid = threadIdx.x;
  const int bx  = blockIdx.x;
  const int m  = bx >> 3;
  const int c  = bx & 7;
  const int s0 = c * CHUNK;
  const int len = min(VDIM - s0, CHUNK);       // 6288, last chunk 6241
  const float* row = P + (size_t)m * VDIM;
  float*       crw = out + PP_OFF + (size_t)m * VDIM;
  u16*        arow = A + (size_t)m * KP;

  if (tid < 32) { f32x4 z = {}; *(f32x4*)(out + (size_t)m * NDIM + c * 128 + tid * 4) = z; }

  u64 best = 0;  // packed (f32 bits << 32) | (0xFFFF - idx); p>0 so bits>0
#define TRK(val, idx) do { \
    u64 pk = ((u64)__float_as_uint(val) << 32) | (u64)(0xFFFFu - (u32)(idx)); \
    best = best > pk ? best : pk; } while (0)
#define GRP(cc) do {                                                     \
    f32x4u va = *(const f32x4u*)(row + (cc));                            \
    f32x4u vb = *(const f32x4u*)(row + (cc) + 4);                        \
    *(f32x4u*)(crw + (cc))     = va;                                     \
    *(f32x4u*)(crw + (cc) + 4) = vb;                                     \
    u16x8 o;                                                             \
    o[0]=f2bf(va[0]); o[1]=f2bf(va[1]); o[2]=f2bf(va[2]); o[3]=f2bf(va[3]); \
    o[4]=f2bf(vb[0]); o[5]=f2bf(vb[1]); o[6]=f2bf(vb[2]); o[7]=f2bf(vb[3]); \
    *(u16x8*)(arow + (cc)) = o;                                          \
    TRK(va[0],(cc)); TRK(va[1],(cc)+1); TRK(va[2],(cc)+2); TRK(va[3],(cc)+3); \
    TRK(vb[0],(cc)+4); TRK(vb[1],(cc)+5); TRK(vb[2],(cc)+6); TRK(vb[3],(cc)+7); \
  } while (0)

  const int ng = len >> 3;                     // 8-elem groups
  int i = tid;
  for (; i + 256 < ng; i += 512) {             // 4 loads in flight
    const int c0 = s0 + (i << 3);
    const int c1 = c0 + 2048;
    GRP(c0);
    GRP(c1);
  }
  if (i < ng) GRP(s0 + (i << 3));
  if (tid < (len & 7)) {                       // straggler elems (last chunk)
    const int col = s0 + (ng << 3) + tid;
    float v = row[col];
    crw[col] = v;
    arow[col] = f2bf(v);
    TRK(v, col);
  }
#undef GRP
#undef TRK
  if (c == 7 && tid < KP - VDIM) arow[VDIM + tid] = 0;  // K-pad (47 elems)

  __shared__ u64 sb[256];
  sb[tid] = best;
  __syncthreads();
  for (int s = 128; s > 0; s >>= 1) {
    if (tid < s) { u64 o = sb[tid + s]; if (o > sb[tid]) sb[tid] = o; }
    __syncthreads();
  }
  if (tid == 0) part[(m << 3) + c] = sb[0];    // plain store, always written
}

// ---------------------------------------------------------------------------
// convw: 64x64 tile transpose+convert W [V][D] f32 -> BT [D][KP] bf16.
// ---------------------------------------------------------------------------
__global__ __launch_bounds__(256) void convw_kernel(const float* __restrict__ W,
                                                    u16* __restrict__ BT)
{
  const int cidx = blockIdx.x;
  __shared__ u16 t[64][72];
  const int tid = threadIdx.x;
  const int dt  = cidx & 15;
  const int vt  = cidx >> 4;          // 0..785; 786*64 == KP exactly
  const int v0  = vt << 6;
  const int d0  = dt << 6;
  const int c16 = tid & 15;
  const int r16 = tid >> 4;
#pragma unroll
  for (int p = 0; p < 4; ++p) {
    const int v  = v0 + p * 16 + r16;
    const int vl = p * 16 + r16;
    float4 w = make_float4(0.f, 0.f, 0.f, 0.f);
    if (v < VDIM) w = *(const float4*)(W + (size_t)v * NDIM + d0 + c16 * 4);
    t[c16 * 4 + 0][vl] = f2bf(w.x);
    t[c16 * 4 + 1][vl] = f2bf(w.y);
    t[c16 * 4 + 2][vl] = f2bf(w.z);
    t[c16 * 4 + 3][vl] = f2bf(w.w);
  }
  __syncthreads();
#pragma unroll
  for (int p = 0; p < 2; ++p) {
    const int dl = p * 32 + (tid >> 3);        // 0..63
    const int vl = (tid & 7) * 8;              // 0..56
    u16x8 o = *(const u16x8*)(&t[dl][vl]);     // 16B-aligned (144B rows)
    *(u16x8*)(BT + (size_t)(d0 + dl) * KP + v0 + vl) = o;
  }
}

// ---------------------------------------------------------------------------
// GEMM: 128x256 tile (staged traffic A*4 + B*4 = 618 MB, -25% vs 128^2),
// BK=32, 8 waves (2m x 4n, 64x64 each), ring-2 LDS (48KB -> 2 blocks/CU,
// grid 512 = exactly 2/CU: cross-block latency hiding, R9-proven),
// single barrier + vmcnt(0) per K-step with full-compute prefetch slack,
// paired-row 8-slot XOR swizzle (0 conflicts, validated R8/R9), split-K=32,
// XCD decode (16 blocks of one kc share one XCD's L2).
// TS=1: plain partial stores to Pp; TS=0: atomicAdd fallback.
// Block 0 also finalizes predictions from part[].
// ---------------------------------------------------------------------------
template <int TS>
__global__ __launch_bounds__(512, 4) void gemm_kernel(const u16* __restrict__ A,
                                                      const u16* __restrict__ BT,
                                                      const u64* __restrict__ part,
                                                      float* __restrict__ out,
                                                      float* __restrict__ Pp)
{
  __shared__ u16 ldsA[2][128 * 32];   // 8KB per buf
  __shared__ u16 ldsB[2][256 * 32];   // 16KB per buf

  const int bx  = blockIdx.x;
  // decode: bx = ((kc>>3)*16 + mn)*8 + (kc&7); the 16 mn-blocks of one kc
  // share bx%8 -> same XCD (kc's A/B k-slabs stay in one L2)
  const int x   = bx & 7;
  const int s   = bx >> 3;
  const int kc  = x + ((s >> 4) << 3);   // 0..31
  const int mn  = s & 15;
  const int mt  = mn & 3;                // 4 m-tiles of 128
  const int nt  = mn >> 2;               // 4 n-tiles of 256
  const int m0  = mt << 7;
  const int n0  = nt << 8;
  const int ks0 = (kc * NST32) / KSPLIT;
  const int ks1 = ((kc + 1) * NST32) / KSPLIT;
  const int tid  = threadIdx.x;
  const int wid  = tid >> 6;
  const int lane = tid & 63;
  const int wr   = wid >> 2;   // 0..1  (m-offset wr*64)
  const int wc   = wid & 3;    // 0..3  (n-offset wc*64)

  if (bx == 0) {  // predictions: reduce 8 chunk-partials per row
    u64 best = part[tid << 3];
#pragma unroll
    for (int c = 1; c < 8; ++c) {
      u64 o = part[(tid << 3) + c];
      best = o > best ? o : best;
    }
    out[PRED_OFF + tid] = (float)(0xFFFF - (int)(best & 0xFFFFu));
  }

  // staging (pre-swizzled source): lane l = sp*8+s covers 16B slot s of 128B
  // row-pair sp within a 16-row issue; LDS written linearly; slot s of pair
  // sp holds global (row 2sp+((s^sp)>>2), kslot (s^sp)&3)  [validated R6-R9]
  const int sp   = lane >> 3;
  const int sx   = (lane & 7) ^ sp;
  const int srow = 2 * sp + (sx >> 2);        // 0..15
  const int skel = (sx & 3) << 3;
  const u16* gA = A  + (size_t)(m0 + wid * 16 + srow) * KP + skel;
  const u16* gB = BT + (size_t)(n0 + wid * 32 + srow) * KP + skel;

  f32x4 acc[4][4] = {};

  // fragment read: row r in 16-band, kslot q4 -> swizzled slot sl
  const int r   = lane & 15;
  const int q4  = lane >> 4;
  const int sl  = (((r & 1) << 2) | q4) ^ ((r >> 1) & 7);
  const int rb2A = (wr * 64 + (r & ~1)) * 32 + sl * 8;
  const int rb2B = (wc * 64 + (r & ~1)) * 32 + sl * 8;

#define STAGE(buf, ks) do {                                              \
    const size_t k_ = (size_t)(ks) << 5;                                 \
    gl_lds16(gA + k_,                 &ldsA[buf][(wid * 16) * 32]);      \
    gl_lds16(gB + k_,                 &ldsB[buf][(wid * 32) * 32]);      \
    gl_lds16(gB + k_ + (size_t)16*KP, &ldsB[buf][(wid * 32 + 16) * 32]); \
  } while (0)

  STAGE(0, ks0);

  int b = 0;
  for (int ks = ks0; ks < ks1; ++ks) {
    asm volatile("s_waitcnt vmcnt(0)" ::: "memory");  // buf b landed (mine)
    __builtin_amdgcn_s_barrier();                     // ..and everyone's;
                                                      // also: reads of b^1 done
    if (ks + 1 < ks1) STAGE(b ^ 1, ks + 1);           // prefetch next step

    const u16* lA = ldsA[b];
    const u16* lB = ldsB[b];
    bf16x8 av[4], bv[4];
#pragma unroll
    for (int i = 0; i < 4; ++i) av[i] = *(const bf16x8*)(lA + rb2A + i * 512);
#pragma unroll
    for (int j = 0; j < 4; ++j) bv[j] = *(const bf16x8*)(lB + rb2B + j * 512);

    __builtin_amdgcn_s_setprio(1);
#pragma unroll
    for (int i = 0; i < 4; ++i)
#pragma unroll
      for (int j = 0; j < 4; ++j)
        acc[i][j] = __builtin_amdgcn_mfma_f32_16x16x32_bf16(av[i], bv[j], acc[i][j], 0, 0, 0);
    __builtin_amdgcn_s_setprio(0);
    __builtin_amdgcn_sched_barrier(0);
    b ^= 1;
  }
#undef STAGE

  const int col = lane & 15;
  if (TS) {
    // plain partial-tile store: Pp[bx][128][256]
    float* pp = Pp + (size_t)bx * 32768;
#pragma unroll
    for (int i = 0; i < 4; ++i)
#pragma unroll
      for (int j = 0; j < 4; ++j)
#pragma unroll
        for (int rr = 0; rr < 4; ++rr) {
          const int mm = wr * 64 + i * 16 + q4 * 4 + rr;
          const int nn = wc * 64 + j * 16 + col;
          pp[mm * 256 + nn] = acc[i][j][rr];
        }
  } else {
#pragma unroll
    for (int i = 0; i < 4; ++i)
#pragma unroll
      for (int j = 0; j < 4; ++j)
#pragma unroll
        for (int rr = 0; rr < 4; ++rr) {
          const int mm = m0 + wr * 64 + i * 16 + q4 * 4 + rr;
          const int nn = n0 + wc * 64 + j * 16 + col;
          atomicAdd(out + (size_t)mm * NDIM + nn, acc[i][j][rr]);
        }
  }
}

// ---------------------------------------------------------------------------
// reduce: out[m][n] = sum over 32 kc-partials. 512 blocks x 256 thr; each
// thread owns one f32x4 n-quad. 32 independent 16B loads, 4 accumulators.
// ---------------------------------------------------------------------------
__global__ __launch_bounds__(256) void reduce_kernel(const float* __restrict__ Pp,
                                                     float* __restrict__ out)
{
  const int t   = blockIdx.x * 256 + threadIdx.x;  // 0..131071
  const int m   = t >> 8;                          // 0..511
  const int n0q = (t & 255) << 2;                  // 0..1020
  const int mt  = m >> 7;                          // 0..3
  const int nt  = n0q >> 8;                        // 0..3
  const size_t base = (size_t)(m & 127) * 256 + (n0q & 255);

  f32x4 sacc[4] = {};
#pragma unroll
  for (int kc = 0; kc < 32; ++kc) {
    const int bxp = (((kc >> 3) * 16 + (nt << 2) + mt) << 3) + (kc & 7);
    f32x4 v = *(const f32x4*)(Pp + (size_t)bxp * 32768 + base);
    sacc[kc & 3] += v;
  }
  f32x4 rsum = (sacc[0] + sacc[1]) + (sacc[2] + sacc[3]);
  *(f32x4*)(out + (size_t)m * NDIM + n0q) = rsum;
}

// ---------------------------------------------------------------------------
extern "C" void kernel_launch(void* const* d_in, const int* in_sizes, int n_in,
                              void* d_out, int out_size, void* d_ws, size_t ws_size,
                              hipStream_t stream) {
  const float* P = (const float*)d_in[0];   // [512][50257]
  const float* W = (const float*)d_in[1];   // [50257][1024]
  float* out = (float*)d_out;
  u64* part = (u64*)d_ws;                               // 512 x 8 u64 (32KB)
  u16* A  = (u16*)((char*)d_ws + 65536);                // [512][KP] bf16
  u16* BT = A + (size_t)MROWS * KP;                     // [1024][KP] bf16
  const size_t pp_off = 65536 + (size_t)MROWS * KP * 2 + (size_t)NDIM * KP * 2;
  const size_t pp_bytes = (size_t)512 * 32768 * 4;      // 67.1 MB
  float* Pp = (float*)((char*)d_ws + pp_off);
  const bool two_stage = (ws_size >= pp_off + pp_bytes);

  prep_kernel<<<NPREP, 256, 0, stream>>>(P, out, A, part);
  convw_kernel<<<NCONVW, 256, 0, stream>>>(W, BT);
  if (two_stage) {
    gemm_kernel<1><<<512, 512, 0, stream>>>(A, BT, part, out, Pp);
    reduce_kernel<<<512, 256, 0, stream>>>(Pp, out);
  } else {
    gemm_kernel<0><<<512, 512, 0, stream>>>(A, BT, part, out, Pp);
  }
}